// Round 10
// baseline (657.008 us; speedup 1.0000x reference)
//
#include <hip/hip_runtime.h>

#define NN 10000
#define NE 320000
#define F  128
#define BLK 256

// ---------- bf16 helpers (storage-only; all accumulation fp32) ----------
__device__ __forceinline__ float bf2f(unsigned v16) {
    return __uint_as_float(v16 << 16);
}
__device__ __forceinline__ unsigned f2bf(float f) {           // round-to-nearest-even
    unsigned u = __float_as_uint(f);
    return (u + 0x7FFFu + ((u >> 16) & 1u)) >> 16;
}
__device__ __forceinline__ unsigned pack2(float lo, float hi) {
    return f2bf(lo) | (f2bf(hi) << 16);
}
__device__ __forceinline__ void unpack8(uint4 q, float* v) {
    v[0] = bf2f(q.x & 0xffffu); v[1] = bf2f(q.x >> 16);
    v[2] = bf2f(q.y & 0xffffu); v[3] = bf2f(q.y >> 16);
    v[4] = bf2f(q.z & 0xffffu); v[5] = bf2f(q.z >> 16);
    v[6] = bf2f(q.w & 0xffffu); v[7] = bf2f(q.w >> 16);
}

// ---------- CSR build (round-6 proven) ----------
__global__ void count_kernel(const int* __restrict__ dst, int* __restrict__ deg) {
    int e = blockIdx.x * 256 + threadIdx.x;
    if (e < NE) atomicAdd(&deg[dst[e]], 1);
}

__global__ __launch_bounds__(1024) void scan_kernel(const int* __restrict__ deg,
                                                    int* __restrict__ offs,
                                                    int* __restrict__ cursor,
                                                    float* __restrict__ invdeg) {
    __shared__ int s[1024];
    int t = threadIdx.x;
    int lo = t * 10;
    int hi = min(lo + 10, NN);
    int sum = 0;
    for (int i = lo; i < hi; ++i) sum += deg[i];
    s[t] = sum;
    __syncthreads();
    for (int off = 1; off < 1024; off <<= 1) {
        int v = (t >= off) ? s[t - off] : 0;
        __syncthreads();
        s[t] += v;
        __syncthreads();
    }
    int base = s[t] - sum;  // exclusive prefix
    for (int i = lo; i < hi; ++i) {
        int c = deg[i];
        offs[i]   = base;
        cursor[i] = base;
        invdeg[i] = 1.0f / (float)c;
        base += c;
    }
    if (t == 0) offs[NN] = NE;
}

__global__ void fill_kernel(const int* __restrict__ dst, const int* __restrict__ src,
                            int* __restrict__ cursor, int* __restrict__ csr,
                            int* __restrict__ csrc) {
    int e = blockIdx.x * 256 + threadIdx.x;
    if (e < NE) {
        int p = atomicAdd(&cursor[dst[e]], 1);
        csr[p] = e;
        csrc[p] = src[e];
    }
}

// ---------- layer-1 seg-mean: fp32 edge_feats -> bf16 nodeA ----------
__global__ __launch_bounds__(256) void seg_mean_k(const float4* __restrict__ ef,
                                                  const int* __restrict__ idx,
                                                  const int* __restrict__ offs,
                                                  const float* __restrict__ invdeg,
                                                  ushort4* __restrict__ Out) {
    __shared__ float4 red[8][32];
    int t  = threadIdx.x;
    int ns = t >> 7, es = (t >> 5) & 3, ch = t & 31;
    int n  = blockIdx.x * 2 + ns;
    int a = offs[n], bnd = offs[n + 1];

    float ax = 0.f, ay = 0.f, az = 0.f, aw = 0.f;
    int i = a + es;
    for (; i + 12 < bnd; i += 16) {
        int s0 = idx[i], s1 = idx[i + 4], s2 = idx[i + 8], s3 = idx[i + 12];
        float4 v0 = ef[(size_t)s0 * 32 + ch];
        float4 v1 = ef[(size_t)s1 * 32 + ch];
        float4 v2 = ef[(size_t)s2 * 32 + ch];
        float4 v3 = ef[(size_t)s3 * 32 + ch];
        ax += v0.x + v1.x + v2.x + v3.x;
        ay += v0.y + v1.y + v2.y + v3.y;
        az += v0.z + v1.z + v2.z + v3.z;
        aw += v0.w + v1.w + v2.w + v3.w;
    }
    for (; i < bnd; i += 4) {
        float4 v0 = ef[(size_t)idx[i] * 32 + ch];
        ax += v0.x; ay += v0.y; az += v0.z; aw += v0.w;
    }

    red[t >> 5][ch] = make_float4(ax, ay, az, aw);
    __syncthreads();
    if (t < 64) {
        int ns2 = t >> 5, c2 = t & 31;
        float4 r0 = red[ns2 * 4 + 0][c2];
        float4 r1 = red[ns2 * 4 + 1][c2];
        float4 r2 = red[ns2 * 4 + 2][c2];
        float4 r3 = red[ns2 * 4 + 3][c2];
        int n2 = blockIdx.x * 2 + ns2;
        float sc = invdeg[n2];
        ushort4 o;
        o.x = (unsigned short)f2bf((r0.x + r1.x + r2.x + r3.x) * sc);
        o.y = (unsigned short)f2bf((r0.y + r1.y + r2.y + r3.y) * sc);
        o.z = (unsigned short)f2bf((r0.z + r1.z + r2.z + r3.z) * sc);
        o.w = (unsigned short)f2bf((r0.w + r1.w + r2.w + r3.w) * sc);
        Out[(size_t)n2 * 32 + c2] = o;   // row = 32 x ushort4 = 128 bf16
    }
}

// ---------- relu-gather (bf16 -> bf16) ----------
__global__ __launch_bounds__(256) void relu_gather_k(const uint4* __restrict__ T,
                                                     const int* __restrict__ idx,
                                                     const int* __restrict__ offs,
                                                     const float* __restrict__ bias,
                                                     const float* __restrict__ invdeg,
                                                     uint4* __restrict__ Out) {
    __shared__ float red[16][16][8];
    int t  = threadIdx.x;
    int ns = t >> 7, es = (t >> 4) & 7, ch = t & 15;
    int n  = blockIdx.x * 2 + ns;
    int a = offs[n], bnd = offs[n + 1];

    float zn[8], bb[8], acc[8];
    unpack8(T[(size_t)n * 16 + ch], zn);
#pragma unroll
    for (int j = 0; j < 8; ++j) { bb[j] = bias[ch * 8 + j]; acc[j] = 0.f; }

    int i = a + es;
    for (; i + 24 < bnd; i += 32) {
        int s0 = idx[i], s1 = idx[i + 8], s2 = idx[i + 16], s3 = idx[i + 24];
        uint4 q0 = T[(size_t)s0 * 16 + ch];
        uint4 q1 = T[(size_t)s1 * 16 + ch];
        uint4 q2 = T[(size_t)s2 * 16 + ch];
        uint4 q3 = T[(size_t)s3 * 16 + ch];
        float v[8];
        unpack8(q0, v);
#pragma unroll
        for (int j = 0; j < 8; ++j) acc[j] += fmaxf(0.5f * (v[j] + zn[j]) + bb[j], 0.f);
        unpack8(q1, v);
#pragma unroll
        for (int j = 0; j < 8; ++j) acc[j] += fmaxf(0.5f * (v[j] + zn[j]) + bb[j], 0.f);
        unpack8(q2, v);
#pragma unroll
        for (int j = 0; j < 8; ++j) acc[j] += fmaxf(0.5f * (v[j] + zn[j]) + bb[j], 0.f);
        unpack8(q3, v);
#pragma unroll
        for (int j = 0; j < 8; ++j) acc[j] += fmaxf(0.5f * (v[j] + zn[j]) + bb[j], 0.f);
    }
    for (; i < bnd; i += 8) {
        uint4 q = T[(size_t)idx[i] * 16 + ch];
        float v[8];
        unpack8(q, v);
#pragma unroll
        for (int j = 0; j < 8; ++j) acc[j] += fmaxf(0.5f * (v[j] + zn[j]) + bb[j], 0.f);
    }

#pragma unroll
    for (int j = 0; j < 8; ++j) red[t >> 4][ch][j] = acc[j];
    __syncthreads();
    if (t < 32) {
        int ns2 = t >> 4, c2 = t & 15;
        float s[8];
#pragma unroll
        for (int j = 0; j < 8; ++j) s[j] = 0.f;
#pragma unroll
        for (int sl = 0; sl < 8; ++sl)
#pragma unroll
            for (int j = 0; j < 8; ++j) s[j] += red[ns2 * 8 + sl][c2][j];
        int n2 = blockIdx.x * 2 + ns2;
        float sc = invdeg[n2];
        uint4 o;
        o.x = pack2(s[0] * sc, s[1] * sc);
        o.y = pack2(s[2] * sc, s[3] * sc);
        o.z = pack2(s[4] * sc, s[5] * sc);
        o.w = pack2(s[6] * sc, s[7] * sc);
        Out[(size_t)n2 * 16 + c2] = o;
    }
}

// ---------- sum-gather (bf16) + fused fp32 matvec -> bf16 z ----------
template <int OUT>
__global__ __launch_bounds__(256) void sum_gemm_k(const uint4* __restrict__ T,
                                                  const int* __restrict__ idx,
                                                  const int* __restrict__ offs,
                                                  const float* __restrict__ Wm,
                                                  unsigned short* __restrict__ Z) {
    __shared__ float red[16][16][8];
    __shared__ float xs[2][128];
    int t  = threadIdx.x;
    int ns = t >> 7, es = (t >> 4) & 7, ch = t & 15;
    int n  = blockIdx.x * 2 + ns;
    int a = offs[n], bnd = offs[n + 1];

    float acc[8];
#pragma unroll
    for (int j = 0; j < 8; ++j) acc[j] = 0.f;

    int i = a + es;
    for (; i + 24 < bnd; i += 32) {
        int s0 = idx[i], s1 = idx[i + 8], s2 = idx[i + 16], s3 = idx[i + 24];
        uint4 q0 = T[(size_t)s0 * 16 + ch];
        uint4 q1 = T[(size_t)s1 * 16 + ch];
        uint4 q2 = T[(size_t)s2 * 16 + ch];
        uint4 q3 = T[(size_t)s3 * 16 + ch];
        float v[8];
        unpack8(q0, v);
#pragma unroll
        for (int j = 0; j < 8; ++j) acc[j] += v[j];
        unpack8(q1, v);
#pragma unroll
        for (int j = 0; j < 8; ++j) acc[j] += v[j];
        unpack8(q2, v);
#pragma unroll
        for (int j = 0; j < 8; ++j) acc[j] += v[j];
        unpack8(q3, v);
#pragma unroll
        for (int j = 0; j < 8; ++j) acc[j] += v[j];
    }
    for (; i < bnd; i += 8) {
        uint4 q = T[(size_t)idx[i] * 16 + ch];
        float v[8];
        unpack8(q, v);
#pragma unroll
        for (int j = 0; j < 8; ++j) acc[j] += v[j];
    }

#pragma unroll
    for (int j = 0; j < 8; ++j) red[t >> 4][ch][j] = acc[j];
    __syncthreads();
    if (t < 32) {
        int ns2 = t >> 4, c2 = t & 15;
        float s[8];
#pragma unroll
        for (int j = 0; j < 8; ++j) s[j] = 0.f;
#pragma unroll
        for (int sl = 0; sl < 8; ++sl)
#pragma unroll
            for (int j = 0; j < 8; ++j) s[j] += red[ns2 * 8 + sl][c2][j];
#pragma unroll
        for (int j = 0; j < 8; ++j) xs[ns2][c2 * 8 + j] = s[j];
    }
    __syncthreads();

    // matvec (round-6 proven shape): threads 0..OUT-1, 2 nodes per thread
    if (t < OUT) {
        const float4* wrow = reinterpret_cast<const float4*>(&Wm[(size_t)t * 128]);
        float acc0 = 0.f, acc1 = 0.f;
#pragma unroll 8
        for (int k4 = 0; k4 < 32; ++k4) {
            float4 w  = wrow[k4];
            float4 x0 = *reinterpret_cast<const float4*>(&xs[0][k4 * 4]);
            float4 x1 = *reinterpret_cast<const float4*>(&xs[1][k4 * 4]);
            acc0 += w.x * x0.x + w.y * x0.y + w.z * x0.z + w.w * x0.w;
            acc1 += w.x * x1.x + w.y * x1.y + w.z * x1.z + w.w * x1.w;
        }
        Z[(size_t)(blockIdx.x * 2 + 0) * OUT + t] = (unsigned short)f2bf(acc0);
        Z[(size_t)(blockIdx.x * 2 + 1) * OUT + t] = (unsigned short)f2bf(acc1);
    }
}

// ---------- final edge output ----------
__global__ __launch_bounds__(256) void edge_out(const uint4* __restrict__ z5,
                                                const float* __restrict__ b5,
                                                const int* __restrict__ src,
                                                const int* __restrict__ dst,
                                                float4* __restrict__ outp) {
    int t = blockIdx.x * 256 + threadIdx.x;
    int e = t >> 3, ch = t & 7;
    if (e < NE) {
        float va[8], vb[8];
        unpack8(z5[(size_t)src[e] * 8 + ch], va);
        unpack8(z5[(size_t)dst[e] * 8 + ch], vb);
        float4 r0, r1;
        r0.x = 0.5f * (va[0] + vb[0]) + b5[ch * 8 + 0];
        r0.y = 0.5f * (va[1] + vb[1]) + b5[ch * 8 + 1];
        r0.z = 0.5f * (va[2] + vb[2]) + b5[ch * 8 + 2];
        r0.w = 0.5f * (va[3] + vb[3]) + b5[ch * 8 + 3];
        r1.x = 0.5f * (va[4] + vb[4]) + b5[ch * 8 + 4];
        r1.y = 0.5f * (va[5] + vb[5]) + b5[ch * 8 + 5];
        r1.z = 0.5f * (va[6] + vb[6]) + b5[ch * 8 + 6];
        r1.w = 0.5f * (va[7] + vb[7]) + b5[ch * 8 + 7];
        outp[(size_t)e * 16 + ch * 2 + 0] = r0;
        outp[(size_t)e * 16 + ch * 2 + 1] = r1;
    }
}

extern "C" void kernel_launch(void* const* d_in, const int* in_sizes, int n_in,
                              void* d_out, int out_size, void* d_ws, size_t ws_size,
                              hipStream_t stream) {
    const float* ef  = (const float*)d_in[0];
    const int*   src = (const int*)d_in[1];
    const int*   dst = (const int*)d_in[2];
    const float* W1 = (const float*)d_in[3];  const float* b1 = (const float*)d_in[4];
    const float* W2 = (const float*)d_in[5];  const float* b2 = (const float*)d_in[6];
    const float* W3 = (const float*)d_in[7];  const float* b3 = (const float*)d_in[8];
    const float* W4 = (const float*)d_in[9];  const float* b4 = (const float*)d_in[10];
    const float* W5 = (const float*)d_in[11]; const float* b5 = (const float*)d_in[12];
    float* out = (float*)d_out;

    char* p = (char*)d_ws;
    auto alloc = [&](size_t bytes) {
        char* r = p;
        p += (bytes + 255) & ~(size_t)255;
        return r;
    };
    int*   deg    = (int*)alloc(NN * 4);
    int*   offs   = (int*)alloc((NN + 1) * 4);
    int*   cursor = (int*)alloc(NN * 4);
    int*   csr    = (int*)alloc((size_t)NE * 4);
    int*   csrc   = (int*)alloc((size_t)NE * 4);
    float* invdeg = (float*)alloc(NN * 4);
    unsigned short* nodeA = (unsigned short*)alloc((size_t)NN * F * 2);  // bf16
    unsigned short* z     = (unsigned short*)alloc((size_t)NN * F * 2);  // bf16

    // CSR build
    hipMemsetAsync(deg, 0, NN * 4, stream);
    count_kernel<<<(NE + 255) / 256, 256, 0, stream>>>(dst, deg);
    scan_kernel<<<1, 1024, 0, stream>>>(deg, offs, cursor, invdeg);
    fill_kernel<<<(NE + 255) / 256, 256, 0, stream>>>(dst, src, cursor, csr, csrc);

    const int GG = NN / 2;                 // 5000 blocks, 2 nodes each
    const uint4* nodeA4 = (const uint4*)nodeA;
    const uint4* z4     = (const uint4*)z;

    // ======== CALIBRATION #2: each node-table pass launched TWICE back-to-back.
    // Each pass is a pure function of an input buffer the duplicate does not
    // modify, so the duplicate writes identical data (output byte-identical).
    // dur ≈ 386us + (T_seg_mean + T_node_passes) + 10 * 2us launch overhead.

    // ---- layer 1 ----
    seg_mean_k<<<GG, BLK, 0, stream>>>((const float4*)ef, csr, offs, invdeg, (ushort4*)nodeA);
    seg_mean_k<<<GG, BLK, 0, stream>>>((const float4*)ef, csr, offs, invdeg, (ushort4*)nodeA);   // CALIB
    sum_gemm_k<128><<<GG, BLK, 0, stream>>>(nodeA4, csrc, offs, W1, z);
    sum_gemm_k<128><<<GG, BLK, 0, stream>>>(nodeA4, csrc, offs, W1, z);                          // CALIB

    // ---- layers 2..4 ----
    const float* Wl[3] = {W2, W3, W4};
    const float* bl[3] = {b1, b2, b3};
    for (int L = 0; L < 3; ++L) {
        relu_gather_k<<<GG, BLK, 0, stream>>>(z4, csrc, offs, bl[L], invdeg, (uint4*)nodeA);
        relu_gather_k<<<GG, BLK, 0, stream>>>(z4, csrc, offs, bl[L], invdeg, (uint4*)nodeA);     // CALIB
        sum_gemm_k<128><<<GG, BLK, 0, stream>>>(nodeA4, csrc, offs, Wl[L], z);
        sum_gemm_k<128><<<GG, BLK, 0, stream>>>(nodeA4, csrc, offs, Wl[L], z);                   // CALIB
    }

    // ---- layer 5 ----
    relu_gather_k<<<GG, BLK, 0, stream>>>(z4, csrc, offs, b4, invdeg, (uint4*)nodeA);
    relu_gather_k<<<GG, BLK, 0, stream>>>(z4, csrc, offs, b4, invdeg, (uint4*)nodeA);            // CALIB
    sum_gemm_k<64><<<GG, BLK, 0, stream>>>(nodeA4, csrc, offs, W5, z);
    sum_gemm_k<64><<<GG, BLK, 0, stream>>>(nodeA4, csrc, offs, W5, z);                           // CALIB

    // ---- final per-edge output (82 MB write) ----
    edge_out<<<(NE * 8 + 255) / 256, BLK, 0, stream>>>(z4, b5, src, dst, (float4*)out);
}

// Round 11
// 445.111 us; speedup vs baseline: 1.4761x; 1.4761x over previous
//
#include <hip/hip_runtime.h>

#define NN 10000
#define NN_P 10048
#define NE 320000
#define F  128
#define BLK 256

// ---------- bf16 helpers (storage-only; all accumulation fp32) ----------
__device__ __forceinline__ float bf2f(unsigned v16) {
    return __uint_as_float(v16 << 16);
}
__device__ __forceinline__ unsigned f2bf(float f) {           // round-to-nearest-even
    unsigned u = __float_as_uint(f);
    return (u + 0x7FFFu + ((u >> 16) & 1u)) >> 16;
}
__device__ __forceinline__ unsigned pack2(float lo, float hi) {
    return f2bf(lo) | (f2bf(hi) << 16);
}
__device__ __forceinline__ void unpack8(uint4 q, float* v) {
    v[0] = bf2f(q.x & 0xffffu); v[1] = bf2f(q.x >> 16);
    v[2] = bf2f(q.y & 0xffffu); v[3] = bf2f(q.y >> 16);
    v[4] = bf2f(q.z & 0xffffu); v[5] = bf2f(q.z >> 16);
    v[6] = bf2f(q.w & 0xffffu); v[7] = bf2f(q.w >> 16);
}

// ---------- CSR build (proven) ----------
__global__ void count_kernel(const int* __restrict__ dst, int* __restrict__ deg) {
    int e = blockIdx.x * 256 + threadIdx.x;
    if (e < NE) atomicAdd(&deg[dst[e]], 1);
}

__global__ __launch_bounds__(1024) void scan_kernel(const int* __restrict__ deg,
                                                    int* __restrict__ offs,
                                                    int* __restrict__ cursor,
                                                    float* __restrict__ invdeg) {
    __shared__ int s[1024];
    int t = threadIdx.x;
    int lo = t * 10;
    int hi = min(lo + 10, NN);
    int sum = 0;
    for (int i = lo; i < hi; ++i) sum += deg[i];
    s[t] = sum;
    __syncthreads();
    for (int off = 1; off < 1024; off <<= 1) {
        int v = (t >= off) ? s[t - off] : 0;
        __syncthreads();
        s[t] += v;
        __syncthreads();
    }
    int base = s[t] - sum;  // exclusive prefix
    for (int i = lo; i < hi; ++i) {
        int c = deg[i];
        offs[i]   = base;
        cursor[i] = base;
        invdeg[i] = 1.0f / (float)c;
        base += c;
    }
    if (t == 0) offs[NN] = NE;
}

__global__ void fill_kernel(const int* __restrict__ dst, const int* __restrict__ src,
                            int* __restrict__ cursor, int* __restrict__ csr,
                            int* __restrict__ csrc) {
    int e = blockIdx.x * 256 + threadIdx.x;
    if (e < NE) {
        int p = atomicAdd(&cursor[dst[e]], 1);
        csr[p] = e;
        csrc[p] = src[e];
    }
}

// ---------- layer-1 seg-mean: fp32 edge_feats -> bf16 m (round-8 proven) ----------
__global__ __launch_bounds__(256) void seg_mean_k(const float4* __restrict__ ef,
                                                  const int* __restrict__ idx,
                                                  const int* __restrict__ offs,
                                                  const float* __restrict__ invdeg,
                                                  ushort4* __restrict__ Out) {
    __shared__ float4 red[8][32];
    int t  = threadIdx.x;
    int ns = t >> 7, es = (t >> 5) & 3, ch = t & 31;
    int n  = blockIdx.x * 2 + ns;
    int a = offs[n], bnd = offs[n + 1];

    float ax = 0.f, ay = 0.f, az = 0.f, aw = 0.f;
    int i = a + es;
    for (; i + 12 < bnd; i += 16) {
        int s0 = idx[i], s1 = idx[i + 4], s2 = idx[i + 8], s3 = idx[i + 12];
        float4 v0 = ef[(size_t)s0 * 32 + ch];
        float4 v1 = ef[(size_t)s1 * 32 + ch];
        float4 v2 = ef[(size_t)s2 * 32 + ch];
        float4 v3 = ef[(size_t)s3 * 32 + ch];
        ax += v0.x + v1.x + v2.x + v3.x;
        ay += v0.y + v1.y + v2.y + v3.y;
        az += v0.z + v1.z + v2.z + v3.z;
        aw += v0.w + v1.w + v2.w + v3.w;
    }
    for (; i < bnd; i += 4) {
        float4 v0 = ef[(size_t)idx[i] * 32 + ch];
        ax += v0.x; ay += v0.y; az += v0.z; aw += v0.w;
    }

    red[t >> 5][ch] = make_float4(ax, ay, az, aw);
    __syncthreads();
    if (t < 64) {
        int ns2 = t >> 5, c2 = t & 31;
        float4 r0 = red[ns2 * 4 + 0][c2];
        float4 r1 = red[ns2 * 4 + 1][c2];
        float4 r2 = red[ns2 * 4 + 2][c2];
        float4 r3 = red[ns2 * 4 + 3][c2];
        int n2 = blockIdx.x * 2 + ns2;
        float sc = invdeg[n2];
        ushort4 o;
        o.x = (unsigned short)f2bf((r0.x + r1.x + r2.x + r3.x) * sc);
        o.y = (unsigned short)f2bf((r0.y + r1.y + r2.y + r3.y) * sc);
        o.z = (unsigned short)f2bf((r0.z + r1.z + r2.z + r3.z) * sc);
        o.w = (unsigned short)f2bf((r0.w + r1.w + r2.w + r3.w) * sc);
        Out[(size_t)n2 * 32 + c2] = o;
    }
}

// ---------- wave-per-node gathers: 4 waves/block, lane = 16 chunks x 4 slots ----------
// MODE 0 (sum):  s[n] (fp32) = sum_{e in(n)} m[src_e]
// MODE 1 (relu): m[n] (bf16) = invdeg[n] * sum_e relu(0.5*(z[src_e]+z[n]) + bias)
template <int MODE>
__global__ __launch_bounds__(256) void gather_w(const uint4* __restrict__ T,
                                                const int* __restrict__ idx,
                                                const int* __restrict__ offs,
                                                const float* __restrict__ bias,
                                                const float* __restrict__ invdeg,
                                                float4* __restrict__ OutF,
                                                uint4* __restrict__ OutB) {
    int t    = threadIdx.x;
    int wave = t >> 6;
    int lane = t & 63;
    int ch   = lane & 15;       // uint4 chunk (8 bf16)
    int slot = lane >> 4;       // 0..3
    int n    = blockIdx.x * 4 + wave;
    if (n >= NN) return;
    int a = offs[n], bnd = offs[n + 1];

    float zn[8], bb[8], acc[8];
    if (MODE == 1) {
        unpack8(T[(size_t)n * 16 + ch], zn);
#pragma unroll
        for (int j = 0; j < 8; ++j) bb[j] = bias[ch * 8 + j];
    }
#pragma unroll
    for (int j = 0; j < 8; ++j) acc[j] = 0.f;

    int i = a + slot;
    for (; i + 12 < bnd; i += 16) {   // 4 rows in flight per lane
        int s0 = idx[i], s1 = idx[i + 4], s2 = idx[i + 8], s3 = idx[i + 12];
        uint4 q0 = T[(size_t)s0 * 16 + ch];
        uint4 q1 = T[(size_t)s1 * 16 + ch];
        uint4 q2 = T[(size_t)s2 * 16 + ch];
        uint4 q3 = T[(size_t)s3 * 16 + ch];
        float v[8];
        unpack8(q0, v);
#pragma unroll
        for (int j = 0; j < 8; ++j)
            acc[j] += (MODE == 1) ? fmaxf(0.5f * (v[j] + zn[j]) + bb[j], 0.f) : v[j];
        unpack8(q1, v);
#pragma unroll
        for (int j = 0; j < 8; ++j)
            acc[j] += (MODE == 1) ? fmaxf(0.5f * (v[j] + zn[j]) + bb[j], 0.f) : v[j];
        unpack8(q2, v);
#pragma unroll
        for (int j = 0; j < 8; ++j)
            acc[j] += (MODE == 1) ? fmaxf(0.5f * (v[j] + zn[j]) + bb[j], 0.f) : v[j];
        unpack8(q3, v);
#pragma unroll
        for (int j = 0; j < 8; ++j)
            acc[j] += (MODE == 1) ? fmaxf(0.5f * (v[j] + zn[j]) + bb[j], 0.f) : v[j];
    }
    for (; i < bnd; i += 4) {
        uint4 q = T[(size_t)idx[i] * 16 + ch];
        float v[8];
        unpack8(q, v);
#pragma unroll
        for (int j = 0; j < 8; ++j)
            acc[j] += (MODE == 1) ? fmaxf(0.5f * (v[j] + zn[j]) + bb[j], 0.f) : v[j];
    }

    // reduce the 4 slots (lanes differing in bits 4,5) via xor-shuffle; no LDS
#pragma unroll
    for (int j = 0; j < 8; ++j) {
        acc[j] += __shfl_xor(acc[j], 16, 64);
        acc[j] += __shfl_xor(acc[j], 32, 64);
    }

    if (slot == 0) {
        if (MODE == 1) {
            float sc = invdeg[n];
            uint4 o;
            o.x = pack2(acc[0] * sc, acc[1] * sc);
            o.y = pack2(acc[2] * sc, acc[3] * sc);
            o.z = pack2(acc[4] * sc, acc[5] * sc);
            o.w = pack2(acc[6] * sc, acc[7] * sc);
            OutB[(size_t)n * 16 + ch] = o;
        } else {
            float4 o0 = make_float4(acc[0], acc[1], acc[2], acc[3]);
            float4 o1 = make_float4(acc[4], acc[5], acc[6], acc[7]);
            OutF[(size_t)n * 32 + ch * 2 + 0] = o0;
            OutF[(size_t)n * 32 + ch * 2 + 1] = o1;
        }
    }
}

// ---------- node GEMM: z[NN x OUT] (bf16) = s[NN_P x 128] (fp32) @ W[OUT x 128]^T ----------
// grid (OUT/64, NN_P/32), block 256; thread = 2 rows x 4 cols (round-2 proven shape)
template <int OUT>
__global__ __launch_bounds__(256) void node_gemm(const float* __restrict__ X,
                                                 const float* __restrict__ Wm,
                                                 unsigned short* __restrict__ Z) {
    int tx = threadIdx.x & 15, ty = threadIdx.x >> 4;
    int c0 = blockIdx.x * 64 + tx * 4;
    int r0 = blockIdx.y * 32 + ty * 2;
    float acc[2][4] = {};
#pragma unroll 8
    for (int k = 0; k < 128; k += 4) {
        float4 x0 = *reinterpret_cast<const float4*>(&X[(size_t)r0 * F + k]);
        float4 x1 = *reinterpret_cast<const float4*>(&X[(size_t)(r0 + 1) * F + k]);
        float4 w0 = *reinterpret_cast<const float4*>(&Wm[(size_t)(c0 + 0) * F + k]);
        float4 w1 = *reinterpret_cast<const float4*>(&Wm[(size_t)(c0 + 1) * F + k]);
        float4 w2 = *reinterpret_cast<const float4*>(&Wm[(size_t)(c0 + 2) * F + k]);
        float4 w3 = *reinterpret_cast<const float4*>(&Wm[(size_t)(c0 + 3) * F + k]);
        acc[0][0] += x0.x * w0.x + x0.y * w0.y + x0.z * w0.z + x0.w * w0.w;
        acc[0][1] += x0.x * w1.x + x0.y * w1.y + x0.z * w1.z + x0.w * w1.w;
        acc[0][2] += x0.x * w2.x + x0.y * w2.y + x0.z * w2.z + x0.w * w2.w;
        acc[0][3] += x0.x * w3.x + x0.y * w3.y + x0.z * w3.z + x0.w * w3.w;
        acc[1][0] += x1.x * w0.x + x1.y * w0.y + x1.z * w0.z + x1.w * w0.w;
        acc[1][1] += x1.x * w1.x + x1.y * w1.y + x1.z * w1.z + x1.w * w1.w;
        acc[1][2] += x1.x * w2.x + x1.y * w2.y + x1.z * w2.z + x1.w * w2.w;
        acc[1][3] += x1.x * w3.x + x1.y * w3.y + x1.z * w3.z + x1.w * w3.w;
    }
#pragma unroll
    for (int i = 0; i < 2; ++i) {
        if (r0 + i < NN) {
            uint2 o;
            o.x = pack2(acc[i][0], acc[i][1]);
            o.y = pack2(acc[i][2], acc[i][3]);
            *reinterpret_cast<uint2*>(&Z[(size_t)(r0 + i) * OUT + c0]) = o;
        }
    }
}

// ---------- final edge output (round-8 proven) ----------
__global__ __launch_bounds__(256) void edge_out(const uint4* __restrict__ z5,
                                                const float* __restrict__ b5,
                                                const int* __restrict__ src,
                                                const int* __restrict__ dst,
                                                float4* __restrict__ outp) {
    int t = blockIdx.x * 256 + threadIdx.x;
    int e = t >> 3, ch = t & 7;
    if (e < NE) {
        float va[8], vb[8];
        unpack8(z5[(size_t)src[e] * 8 + ch], va);
        unpack8(z5[(size_t)dst[e] * 8 + ch], vb);
        float4 r0, r1;
        r0.x = 0.5f * (va[0] + vb[0]) + b5[ch * 8 + 0];
        r0.y = 0.5f * (va[1] + vb[1]) + b5[ch * 8 + 1];
        r0.z = 0.5f * (va[2] + vb[2]) + b5[ch * 8 + 2];
        r0.w = 0.5f * (va[3] + vb[3]) + b5[ch * 8 + 3];
        r1.x = 0.5f * (va[4] + vb[4]) + b5[ch * 8 + 4];
        r1.y = 0.5f * (va[5] + vb[5]) + b5[ch * 8 + 5];
        r1.z = 0.5f * (va[6] + vb[6]) + b5[ch * 8 + 6];
        r1.w = 0.5f * (va[7] + vb[7]) + b5[ch * 8 + 7];
        outp[(size_t)e * 16 + ch * 2 + 0] = r0;
        outp[(size_t)e * 16 + ch * 2 + 1] = r1;
    }
}

extern "C" void kernel_launch(void* const* d_in, const int* in_sizes, int n_in,
                              void* d_out, int out_size, void* d_ws, size_t ws_size,
                              hipStream_t stream) {
    const float* ef  = (const float*)d_in[0];
    const int*   src = (const int*)d_in[1];
    const int*   dst = (const int*)d_in[2];
    const float* W1 = (const float*)d_in[3];  const float* b1 = (const float*)d_in[4];
    const float* W2 = (const float*)d_in[5];  const float* b2 = (const float*)d_in[6];
    const float* W3 = (const float*)d_in[7];  const float* b3 = (const float*)d_in[8];
    const float* W4 = (const float*)d_in[9];  const float* b4 = (const float*)d_in[10];
    const float* W5 = (const float*)d_in[11]; const float* b5 = (const float*)d_in[12];
    float* out = (float*)d_out;

    char* p = (char*)d_ws;
    auto alloc = [&](size_t bytes) {
        char* r = p;
        p += (bytes + 255) & ~(size_t)255;
        return r;
    };
    int*   deg    = (int*)alloc(NN * 4);
    int*   offs   = (int*)alloc((NN + 1) * 4);
    int*   cursor = (int*)alloc(NN * 4);
    int*   csr    = (int*)alloc((size_t)NE * 4);
    int*   csrc   = (int*)alloc((size_t)NE * 4);
    float* invdeg = (float*)alloc(NN * 4);
    unsigned short* m = (unsigned short*)alloc((size_t)NN * F * 2);    // bf16 (gathered)
    float*          s = (float*)alloc((size_t)NN_P * F * 4);           // fp32 (dense GEMM in)
    unsigned short* z = (unsigned short*)alloc((size_t)NN * F * 2);    // bf16 (gathered)

    // CSR build
    hipMemsetAsync(deg, 0, NN * 4, stream);
    count_kernel<<<(NE + 255) / 256, 256, 0, stream>>>(dst, deg);
    scan_kernel<<<1, 1024, 0, stream>>>(deg, offs, cursor, invdeg);
    fill_kernel<<<(NE + 255) / 256, 256, 0, stream>>>(dst, src, cursor, csr, csrc);

    const int GW = (NN + 3) / 4;          // wave-per-node gather grid
    const uint4* m4 = (const uint4*)m;
    const uint4* z4 = (const uint4*)z;
    dim3 g128(2, NN_P / 32), g64(1, NN_P / 32);

    // ---- layer 1 ----
    seg_mean_k<<<NN / 2, BLK, 0, stream>>>((const float4*)ef, csr, offs, invdeg, (ushort4*)m);
    gather_w<0><<<GW, BLK, 0, stream>>>(m4, csrc, offs, nullptr, nullptr, (float4*)s, nullptr);
    node_gemm<128><<<g128, BLK, 0, stream>>>(s, W1, z);

    // ---- layers 2..4 ----
    const float* Wl[3] = {W2, W3, W4};
    const float* bl[3] = {b1, b2, b3};
    for (int L = 0; L < 3; ++L) {
        gather_w<1><<<GW, BLK, 0, stream>>>(z4, csrc, offs, bl[L], invdeg, nullptr, (uint4*)m);
        gather_w<0><<<GW, BLK, 0, stream>>>(m4, csrc, offs, nullptr, nullptr, (float4*)s, nullptr);
        node_gemm<128><<<g128, BLK, 0, stream>>>(s, Wl[L], z);
    }

    // ---- layer 5 ----
    gather_w<1><<<GW, BLK, 0, stream>>>(z4, csrc, offs, b4, invdeg, nullptr, (uint4*)m);
    gather_w<0><<<GW, BLK, 0, stream>>>(m4, csrc, offs, nullptr, nullptr, (float4*)s, nullptr);
    node_gemm<64><<<g64, BLK, 0, stream>>>(s, W5, z);

    // ---- final per-edge output (82 MB write) ----
    edge_out<<<(NE * 8 + 255) / 256, BLK, 0, stream>>>(z4, b5, src, dst, (float4*)out);
}

// Round 12
// 345.542 us; speedup vs baseline: 1.9014x; 1.2882x over previous
//
#include <hip/hip_runtime.h>

#define NN 10000
#define NE 320000
#define F  128
#define BLK 256
#define CAP 96   // bucket capacity; deg = 1+Binom(310000,1e-4), P(deg>96) < 1e-20

// ---------- bf16 helpers (storage-only; all accumulation fp32) ----------
__device__ __forceinline__ float bf2f(unsigned v16) {
    return __uint_as_float(v16 << 16);
}
__device__ __forceinline__ unsigned f2bf(float f) {           // round-to-nearest-even
    unsigned u = __float_as_uint(f);
    return (u + 0x7FFFu + ((u >> 16) & 1u)) >> 16;
}
__device__ __forceinline__ unsigned pack2(float lo, float hi) {
    return f2bf(lo) | (f2bf(hi) << 16);
}
__device__ __forceinline__ void unpack8(uint4 q, float* v) {
    v[0] = bf2f(q.x & 0xffffu); v[1] = bf2f(q.x >> 16);
    v[2] = bf2f(q.y & 0xffffu); v[3] = bf2f(q.y >> 16);
    v[4] = bf2f(q.z & 0xffffu); v[5] = bf2f(q.z >> 16);
    v[6] = bf2f(q.w & 0xffffu); v[7] = bf2f(q.w >> 16);
}

// ---------- bucket-CSR build: ONE pass over edges (replaces count+scan+fill) ----------
__global__ void bucket_fill(const int* __restrict__ dst, const int* __restrict__ src,
                            int* __restrict__ cnt, int* __restrict__ buck,
                            int* __restrict__ bucksrc) {
    int e = blockIdx.x * 256 + threadIdx.x;
    if (e < NE) {
        int d = dst[e];
        int p = atomicAdd(&cnt[d], 1);
        buck[d * CAP + p]    = e;
        bucksrc[d * CAP + p] = src[e];
    }
}

// ---------- layer-1 seg-mean: fp32 edge_feats -> bf16 m (round-8 proven shape) ----------
__global__ __launch_bounds__(256) void seg_mean_k(const float4* __restrict__ ef,
                                                  const int* __restrict__ buck,
                                                  const int* __restrict__ cnt,
                                                  ushort4* __restrict__ Out) {
    __shared__ float4 red[8][32];
    int t  = threadIdx.x;
    int ns = t >> 7, es = (t >> 5) & 3, ch = t & 31;
    int n  = blockIdx.x * 2 + ns;
    int a = n * CAP, c = cnt[n], bnd = a + c;

    float ax = 0.f, ay = 0.f, az = 0.f, aw = 0.f;
    int i = a + es;
    for (; i + 12 < bnd; i += 16) {
        int s0 = buck[i], s1 = buck[i + 4], s2 = buck[i + 8], s3 = buck[i + 12];
        float4 v0 = ef[(size_t)s0 * 32 + ch];
        float4 v1 = ef[(size_t)s1 * 32 + ch];
        float4 v2 = ef[(size_t)s2 * 32 + ch];
        float4 v3 = ef[(size_t)s3 * 32 + ch];
        ax += v0.x + v1.x + v2.x + v3.x;
        ay += v0.y + v1.y + v2.y + v3.y;
        az += v0.z + v1.z + v2.z + v3.z;
        aw += v0.w + v1.w + v2.w + v3.w;
    }
    for (; i < bnd; i += 4) {
        float4 v0 = ef[(size_t)buck[i] * 32 + ch];
        ax += v0.x; ay += v0.y; az += v0.z; aw += v0.w;
    }

    red[t >> 5][ch] = make_float4(ax, ay, az, aw);
    __syncthreads();
    if (t < 64) {
        int ns2 = t >> 5, c2 = t & 31;
        float4 r0 = red[ns2 * 4 + 0][c2];
        float4 r1 = red[ns2 * 4 + 1][c2];
        float4 r2 = red[ns2 * 4 + 2][c2];
        float4 r3 = red[ns2 * 4 + 3][c2];
        int n2 = blockIdx.x * 2 + ns2;
        float sc = 1.0f / (float)cnt[n2];
        ushort4 o;
        o.x = (unsigned short)f2bf((r0.x + r1.x + r2.x + r3.x) * sc);
        o.y = (unsigned short)f2bf((r0.y + r1.y + r2.y + r3.y) * sc);
        o.z = (unsigned short)f2bf((r0.z + r1.z + r2.z + r3.z) * sc);
        o.w = (unsigned short)f2bf((r0.w + r1.w + r2.w + r3.w) * sc);
        Out[(size_t)n2 * 32 + c2] = o;
    }
}

// ---------- relu-gather (bf16 -> bf16), round-8 proven shape, bucket-indexed ----------
__global__ __launch_bounds__(256) void relu_gather_k(const uint4* __restrict__ T,
                                                     const int* __restrict__ bucksrc,
                                                     const int* __restrict__ cnt,
                                                     const float* __restrict__ bias,
                                                     uint4* __restrict__ Out) {
    __shared__ float red[16][16][8];
    int t  = threadIdx.x;
    int ns = t >> 7, es = (t >> 4) & 7, ch = t & 15;
    int n  = blockIdx.x * 2 + ns;
    int a = n * CAP, bnd = a + cnt[n];

    float zn[8], bb[8], acc[8];
    unpack8(T[(size_t)n * 16 + ch], zn);
#pragma unroll
    for (int j = 0; j < 8; ++j) { bb[j] = bias[ch * 8 + j]; acc[j] = 0.f; }

    int i = a + es;
    for (; i + 24 < bnd; i += 32) {
        int s0 = bucksrc[i], s1 = bucksrc[i + 8], s2 = bucksrc[i + 16], s3 = bucksrc[i + 24];
        uint4 q0 = T[(size_t)s0 * 16 + ch];
        uint4 q1 = T[(size_t)s1 * 16 + ch];
        uint4 q2 = T[(size_t)s2 * 16 + ch];
        uint4 q3 = T[(size_t)s3 * 16 + ch];
        float v[8];
        unpack8(q0, v);
#pragma unroll
        for (int j = 0; j < 8; ++j) acc[j] += fmaxf(0.5f * (v[j] + zn[j]) + bb[j], 0.f);
        unpack8(q1, v);
#pragma unroll
        for (int j = 0; j < 8; ++j) acc[j] += fmaxf(0.5f * (v[j] + zn[j]) + bb[j], 0.f);
        unpack8(q2, v);
#pragma unroll
        for (int j = 0; j < 8; ++j) acc[j] += fmaxf(0.5f * (v[j] + zn[j]) + bb[j], 0.f);
        unpack8(q3, v);
#pragma unroll
        for (int j = 0; j < 8; ++j) acc[j] += fmaxf(0.5f * (v[j] + zn[j]) + bb[j], 0.f);
    }
    for (; i < bnd; i += 8) {
        uint4 q = T[(size_t)bucksrc[i] * 16 + ch];
        float v[8];
        unpack8(q, v);
#pragma unroll
        for (int j = 0; j < 8; ++j) acc[j] += fmaxf(0.5f * (v[j] + zn[j]) + bb[j], 0.f);
    }

#pragma unroll
    for (int j = 0; j < 8; ++j) red[t >> 4][ch][j] = acc[j];
    __syncthreads();
    if (t < 32) {
        int ns2 = t >> 4, c2 = t & 15;
        float s[8];
#pragma unroll
        for (int j = 0; j < 8; ++j) s[j] = 0.f;
#pragma unroll
        for (int sl = 0; sl < 8; ++sl)
#pragma unroll
            for (int j = 0; j < 8; ++j) s[j] += red[ns2 * 8 + sl][c2][j];
        int n2 = blockIdx.x * 2 + ns2;
        float sc = 1.0f / (float)cnt[n2];
        uint4 o;
        o.x = pack2(s[0] * sc, s[1] * sc);
        o.y = pack2(s[2] * sc, s[3] * sc);
        o.z = pack2(s[4] * sc, s[5] * sc);
        o.w = pack2(s[6] * sc, s[7] * sc);
        Out[(size_t)n2 * 16 + c2] = o;
    }
}

// ---------- sum-gather (bf16) + fused fp32 matvec -> bf16 z (round-8 proven) ----------
template <int OUT>
__global__ __launch_bounds__(256) void sum_gemm_k(const uint4* __restrict__ T,
                                                  const int* __restrict__ bucksrc,
                                                  const int* __restrict__ cnt,
                                                  const float* __restrict__ Wm,
                                                  unsigned short* __restrict__ Z) {
    __shared__ float red[16][16][8];
    __shared__ float xs[2][128];
    int t  = threadIdx.x;
    int ns = t >> 7, es = (t >> 4) & 7, ch = t & 15;
    int n  = blockIdx.x * 2 + ns;
    int a = n * CAP, bnd = a + cnt[n];

    float acc[8];
#pragma unroll
    for (int j = 0; j < 8; ++j) acc[j] = 0.f;

    int i = a + es;
    for (; i + 24 < bnd; i += 32) {
        int s0 = bucksrc[i], s1 = bucksrc[i + 8], s2 = bucksrc[i + 16], s3 = bucksrc[i + 24];
        uint4 q0 = T[(size_t)s0 * 16 + ch];
        uint4 q1 = T[(size_t)s1 * 16 + ch];
        uint4 q2 = T[(size_t)s2 * 16 + ch];
        uint4 q3 = T[(size_t)s3 * 16 + ch];
        float v[8];
        unpack8(q0, v);
#pragma unroll
        for (int j = 0; j < 8; ++j) acc[j] += v[j];
        unpack8(q1, v);
#pragma unroll
        for (int j = 0; j < 8; ++j) acc[j] += v[j];
        unpack8(q2, v);
#pragma unroll
        for (int j = 0; j < 8; ++j) acc[j] += v[j];
        unpack8(q3, v);
#pragma unroll
        for (int j = 0; j < 8; ++j) acc[j] += v[j];
    }
    for (; i < bnd; i += 8) {
        uint4 q = T[(size_t)bucksrc[i] * 16 + ch];
        float v[8];
        unpack8(q, v);
#pragma unroll
        for (int j = 0; j < 8; ++j) acc[j] += v[j];
    }

#pragma unroll
    for (int j = 0; j < 8; ++j) red[t >> 4][ch][j] = acc[j];
    __syncthreads();
    if (t < 32) {
        int ns2 = t >> 4, c2 = t & 15;
        float s[8];
#pragma unroll
        for (int j = 0; j < 8; ++j) s[j] = 0.f;
#pragma unroll
        for (int sl = 0; sl < 8; ++sl)
#pragma unroll
            for (int j = 0; j < 8; ++j) s[j] += red[ns2 * 8 + sl][c2][j];
#pragma unroll
        for (int j = 0; j < 8; ++j) xs[ns2][c2 * 8 + j] = s[j];
    }
    __syncthreads();

    // matvec: threads 0..OUT-1, 2 nodes per thread (W row reused for both)
    if (t < OUT) {
        const float4* wrow = reinterpret_cast<const float4*>(&Wm[(size_t)t * 128]);
        float acc0 = 0.f, acc1 = 0.f;
#pragma unroll 8
        for (int k4 = 0; k4 < 32; ++k4) {
            float4 w  = wrow[k4];
            float4 x0 = *reinterpret_cast<const float4*>(&xs[0][k4 * 4]);
            float4 x1 = *reinterpret_cast<const float4*>(&xs[1][k4 * 4]);
            acc0 += w.x * x0.x + w.y * x0.y + w.z * x0.z + w.w * x0.w;
            acc1 += w.x * x1.x + w.y * x1.y + w.z * x1.z + w.w * x1.w;
        }
        Z[(size_t)(blockIdx.x * 2 + 0) * OUT + t] = (unsigned short)f2bf(acc0);
        Z[(size_t)(blockIdx.x * 2 + 1) * OUT + t] = (unsigned short)f2bf(acc1);
    }
}

// ---------- final edge output (round-8 proven) ----------
__global__ __launch_bounds__(256) void edge_out(const uint4* __restrict__ z5,
                                                const float* __restrict__ b5,
                                                const int* __restrict__ src,
                                                const int* __restrict__ dst,
                                                float4* __restrict__ outp) {
    int t = blockIdx.x * 256 + threadIdx.x;
    int e = t >> 3, ch = t & 7;
    if (e < NE) {
        float va[8], vb[8];
        unpack8(z5[(size_t)src[e] * 8 + ch], va);
        unpack8(z5[(size_t)dst[e] * 8 + ch], vb);
        float4 r0, r1;
        r0.x = 0.5f * (va[0] + vb[0]) + b5[ch * 8 + 0];
        r0.y = 0.5f * (va[1] + vb[1]) + b5[ch * 8 + 1];
        r0.z = 0.5f * (va[2] + vb[2]) + b5[ch * 8 + 2];
        r0.w = 0.5f * (va[3] + vb[3]) + b5[ch * 8 + 3];
        r1.x = 0.5f * (va[4] + vb[4]) + b5[ch * 8 + 4];
        r1.y = 0.5f * (va[5] + vb[5]) + b5[ch * 8 + 5];
        r1.z = 0.5f * (va[6] + vb[6]) + b5[ch * 8 + 6];
        r1.w = 0.5f * (va[7] + vb[7]) + b5[ch * 8 + 7];
        outp[(size_t)e * 16 + ch * 2 + 0] = r0;
        outp[(size_t)e * 16 + ch * 2 + 1] = r1;
    }
}

extern "C" void kernel_launch(void* const* d_in, const int* in_sizes, int n_in,
                              void* d_out, int out_size, void* d_ws, size_t ws_size,
                              hipStream_t stream) {
    const float* ef  = (const float*)d_in[0];
    const int*   src = (const int*)d_in[1];
    const int*   dst = (const int*)d_in[2];
    const float* W1 = (const float*)d_in[3];  const float* b1 = (const float*)d_in[4];
    const float* W2 = (const float*)d_in[5];  const float* b2 = (const float*)d_in[6];
    const float* W3 = (const float*)d_in[7];  const float* b3 = (const float*)d_in[8];
    const float* W4 = (const float*)d_in[9];  const float* b4 = (const float*)d_in[10];
    const float* W5 = (const float*)d_in[11]; const float* b5 = (const float*)d_in[12];
    float* out = (float*)d_out;

    char* p = (char*)d_ws;
    auto alloc = [&](size_t bytes) {
        char* r = p;
        p += (bytes + 255) & ~(size_t)255;
        return r;
    };
    int* cnt     = (int*)alloc(NN * 4);
    int* buck    = (int*)alloc((size_t)NN * CAP * 4);
    int* bucksrc = (int*)alloc((size_t)NN * CAP * 4);
    unsigned short* m = (unsigned short*)alloc((size_t)NN * F * 2);  // bf16
    unsigned short* z = (unsigned short*)alloc((size_t)NN * F * 2);  // bf16

    // ---- bucket-CSR build: 2 dispatches (was 4) ----
    hipMemsetAsync(cnt, 0, NN * 4, stream);
    bucket_fill<<<(NE + 255) / 256, 256, 0, stream>>>(dst, src, cnt, buck, bucksrc);

    const int GG = NN / 2;                 // 5000 blocks, 2 nodes each
    const uint4* m4 = (const uint4*)m;
    const uint4* z4 = (const uint4*)z;

    // ---- layer 1 ----
    seg_mean_k<<<GG, BLK, 0, stream>>>((const float4*)ef, buck, cnt, (ushort4*)m);
    sum_gemm_k<128><<<GG, BLK, 0, stream>>>(m4, bucksrc, cnt, W1, z);

    // ---- layers 2..4 (prev layer's edge compute fused into the relu gather) ----
    const float* Wl[3] = {W2, W3, W4};
    const float* bl[3] = {b1, b2, b3};
    for (int L = 0; L < 3; ++L) {
        relu_gather_k<<<GG, BLK, 0, stream>>>(z4, bucksrc, cnt, bl[L], (uint4*)m);
        sum_gemm_k<128><<<GG, BLK, 0, stream>>>(m4, bucksrc, cnt, Wl[L], z);
    }

    // ---- layer 5 ----
    relu_gather_k<<<GG, BLK, 0, stream>>>(z4, bucksrc, cnt, b4, (uint4*)m);
    sum_gemm_k<64><<<GG, BLK, 0, stream>>>(m4, bucksrc, cnt, W5, z);

    // ---- final per-edge output (82 MB write) ----
    edge_out<<<(NE * 8 + 255) / 256, BLK, 0, stream>>>(z4, b5, src, dst, (float4*)out);
}

// Round 13
// 286.214 us; speedup vs baseline: 2.2955x; 1.2073x over previous
//
#include <hip/hip_runtime.h>

#define NN 10000
#define NE 320000
#define F  128
#define BLK 256
#define CAP 96   // bucket capacity; deg = 1+Binom(310000,1e-4), P(deg>96) < 1e-20

// ---------- bf16 helpers (storage-only; all accumulation fp32) ----------
__device__ __forceinline__ float bf2f(unsigned v16) {
    return __uint_as_float(v16 << 16);
}
__device__ __forceinline__ unsigned f2bf(float f) {           // round-to-nearest-even
    unsigned u = __float_as_uint(f);
    return (u + 0x7FFFu + ((u >> 16) & 1u)) >> 16;
}
__device__ __forceinline__ unsigned pack2(float lo, float hi) {
    return f2bf(lo) | (f2bf(hi) << 16);
}
__device__ __forceinline__ void unpack8(uint4 q, float* v) {
    v[0] = bf2f(q.x & 0xffffu); v[1] = bf2f(q.x >> 16);
    v[2] = bf2f(q.y & 0xffffu); v[3] = bf2f(q.y >> 16);
    v[4] = bf2f(q.z & 0xffffu); v[5] = bf2f(q.z >> 16);
    v[6] = bf2f(q.w & 0xffffu); v[7] = bf2f(q.w >> 16);
}

// ---------- bucket-CSR build: ONE pass over edges ----------
__global__ void bucket_fill(const int* __restrict__ dst, const int* __restrict__ src,
                            int* __restrict__ cnt, int* __restrict__ buck,
                            int* __restrict__ bucksrc) {
    int e = blockIdx.x * 256 + threadIdx.x;
    if (e < NE) {
        int d = dst[e];
        int p = atomicAdd(&cnt[d], 1);
        buck[d * CAP + p]    = e;
        bucksrc[d * CAP + p] = src[e];
    }
}

// ---------- layer-1 seg-mean: fp32 edge_feats -> bf16 m ----------
// block = 2 nodes x 4 slots x 32 float4-chunks; 8 rows in flight per thread
__global__ __launch_bounds__(256) void seg_mean_k(const float4* __restrict__ ef,
                                                  const int* __restrict__ buck,
                                                  const int* __restrict__ cnt,
                                                  ushort4* __restrict__ Out) {
    __shared__ float4 red[8][32];
    int t  = threadIdx.x;
    int ns = t >> 7, es = (t >> 5) & 3, ch = t & 31;
    int n  = blockIdx.x * 2 + ns;
    int a = n * CAP, bnd = a + cnt[n];

    float ax = 0.f, ay = 0.f, az = 0.f, aw = 0.f;
    int i = a + es;
    for (; i + 28 < bnd; i += 32) {       // 8 rows in flight
        int s0 = buck[i],      s1 = buck[i + 4],  s2 = buck[i + 8],  s3 = buck[i + 12];
        int s4 = buck[i + 16], s5 = buck[i + 20], s6 = buck[i + 24], s7 = buck[i + 28];
        float4 v0 = ef[(size_t)s0 * 32 + ch];
        float4 v1 = ef[(size_t)s1 * 32 + ch];
        float4 v2 = ef[(size_t)s2 * 32 + ch];
        float4 v3 = ef[(size_t)s3 * 32 + ch];
        float4 v4 = ef[(size_t)s4 * 32 + ch];
        float4 v5 = ef[(size_t)s5 * 32 + ch];
        float4 v6 = ef[(size_t)s6 * 32 + ch];
        float4 v7 = ef[(size_t)s7 * 32 + ch];
        ax += v0.x + v1.x + v2.x + v3.x + v4.x + v5.x + v6.x + v7.x;
        ay += v0.y + v1.y + v2.y + v3.y + v4.y + v5.y + v6.y + v7.y;
        az += v0.z + v1.z + v2.z + v3.z + v4.z + v5.z + v6.z + v7.z;
        aw += v0.w + v1.w + v2.w + v3.w + v4.w + v5.w + v6.w + v7.w;
    }
    for (; i < bnd; i += 4) {
        float4 v0 = ef[(size_t)buck[i] * 32 + ch];
        ax += v0.x; ay += v0.y; az += v0.z; aw += v0.w;
    }

    red[(t >> 5)][ch] = make_float4(ax, ay, az, aw);
    __syncthreads();
    if (t < 64) {
        int ns2 = t >> 5, c2 = t & 31;
        float4 r0 = red[ns2 * 4 + 0][c2];
        float4 r1 = red[ns2 * 4 + 1][c2];
        float4 r2 = red[ns2 * 4 + 2][c2];
        float4 r3 = red[ns2 * 4 + 3][c2];
        int n2 = blockIdx.x * 2 + ns2;
        float sc = 1.0f / (float)cnt[n2];
        ushort4 o;
        o.x = (unsigned short)f2bf((r0.x + r1.x + r2.x + r3.x) * sc);
        o.y = (unsigned short)f2bf((r0.y + r1.y + r2.y + r3.y) * sc);
        o.z = (unsigned short)f2bf((r0.z + r1.z + r2.z + r3.z) * sc);
        o.w = (unsigned short)f2bf((r0.w + r1.w + r2.w + r3.w) * sc);
        Out[(size_t)n2 * 32 + c2] = o;
    }
}

// ---------- relu-gather (bf16 -> bf16): wave-per-node, shuffle reduce, no LDS ----------
// lane = 4 slots x 16 uint4-chunks; 8 rows in flight per lane
__global__ __launch_bounds__(256) void relu_gather_k(const uint4* __restrict__ T,
                                                     const int* __restrict__ bucksrc,
                                                     const int* __restrict__ cnt,
                                                     const float* __restrict__ bias,
                                                     uint4* __restrict__ Out) {
    int t  = threadIdx.x;
    int nd = t >> 6;            // wave = node
    int lane = t & 63;
    int ch = lane & 15;         // uint4 chunk (8 bf16)
    int es = lane >> 4;         // slot 0..3
    int n  = blockIdx.x * 4 + nd;
    int a = n * CAP, bnd = a + cnt[n];

    float zn[8], bb[8], acc[8];
    unpack8(T[(size_t)n * 16 + ch], zn);
#pragma unroll
    for (int j = 0; j < 8; ++j) { bb[j] = bias[ch * 8 + j]; acc[j] = 0.f; }

    int i = a + es;
    for (; i + 28 < bnd; i += 32) {       // 8 rows in flight
        int s0 = bucksrc[i],      s1 = bucksrc[i + 4],  s2 = bucksrc[i + 8],  s3 = bucksrc[i + 12];
        int s4 = bucksrc[i + 16], s5 = bucksrc[i + 20], s6 = bucksrc[i + 24], s7 = bucksrc[i + 28];
        uint4 q0 = T[(size_t)s0 * 16 + ch];
        uint4 q1 = T[(size_t)s1 * 16 + ch];
        uint4 q2 = T[(size_t)s2 * 16 + ch];
        uint4 q3 = T[(size_t)s3 * 16 + ch];
        uint4 q4 = T[(size_t)s4 * 16 + ch];
        uint4 q5 = T[(size_t)s5 * 16 + ch];
        uint4 q6 = T[(size_t)s6 * 16 + ch];
        uint4 q7 = T[(size_t)s7 * 16 + ch];
        float v[8];
        unpack8(q0, v);
#pragma unroll
        for (int j = 0; j < 8; ++j) acc[j] += fmaxf(0.5f * (v[j] + zn[j]) + bb[j], 0.f);
        unpack8(q1, v);
#pragma unroll
        for (int j = 0; j < 8; ++j) acc[j] += fmaxf(0.5f * (v[j] + zn[j]) + bb[j], 0.f);
        unpack8(q2, v);
#pragma unroll
        for (int j = 0; j < 8; ++j) acc[j] += fmaxf(0.5f * (v[j] + zn[j]) + bb[j], 0.f);
        unpack8(q3, v);
#pragma unroll
        for (int j = 0; j < 8; ++j) acc[j] += fmaxf(0.5f * (v[j] + zn[j]) + bb[j], 0.f);
        unpack8(q4, v);
#pragma unroll
        for (int j = 0; j < 8; ++j) acc[j] += fmaxf(0.5f * (v[j] + zn[j]) + bb[j], 0.f);
        unpack8(q5, v);
#pragma unroll
        for (int j = 0; j < 8; ++j) acc[j] += fmaxf(0.5f * (v[j] + zn[j]) + bb[j], 0.f);
        unpack8(q6, v);
#pragma unroll
        for (int j = 0; j < 8; ++j) acc[j] += fmaxf(0.5f * (v[j] + zn[j]) + bb[j], 0.f);
        unpack8(q7, v);
#pragma unroll
        for (int j = 0; j < 8; ++j) acc[j] += fmaxf(0.5f * (v[j] + zn[j]) + bb[j], 0.f);
    }
    for (; i < bnd; i += 4) {
        uint4 q = T[(size_t)bucksrc[i] * 16 + ch];
        float v[8];
        unpack8(q, v);
#pragma unroll
        for (int j = 0; j < 8; ++j) acc[j] += fmaxf(0.5f * (v[j] + zn[j]) + bb[j], 0.f);
    }

    // reduce 4 slots across lanes (bits 4,5) — no LDS, no barrier
#pragma unroll
    for (int j = 0; j < 8; ++j) {
        acc[j] += __shfl_xor(acc[j], 16, 64);
        acc[j] += __shfl_xor(acc[j], 32, 64);
    }

    if (es == 0) {
        float sc = 1.0f / (float)cnt[n];
        uint4 o;
        o.x = pack2(acc[0] * sc, acc[1] * sc);
        o.y = pack2(acc[2] * sc, acc[3] * sc);
        o.z = pack2(acc[4] * sc, acc[5] * sc);
        o.w = pack2(acc[6] * sc, acc[7] * sc);
        Out[(size_t)n * 16 + ch] = o;
    }
}

// ---------- sum-gather (bf16, wave-per-node) + fused fp32 matvec (W reuse x4) ----------
template <int OUT>
__global__ __launch_bounds__(256) void sum_gemm_k(const uint4* __restrict__ T,
                                                  const int* __restrict__ bucksrc,
                                                  const int* __restrict__ cnt,
                                                  const float* __restrict__ Wm,
                                                  unsigned short* __restrict__ Z) {
    __shared__ float xs[4][128];
    int t  = threadIdx.x;
    int nd = t >> 6;
    int lane = t & 63;
    int ch = lane & 15;
    int es = lane >> 4;
    int n  = blockIdx.x * 4 + nd;
    int a = n * CAP, bnd = a + cnt[n];

    float acc[8];
#pragma unroll
    for (int j = 0; j < 8; ++j) acc[j] = 0.f;

    int i = a + es;
    for (; i + 28 < bnd; i += 32) {       // 8 rows in flight
        int s0 = bucksrc[i],      s1 = bucksrc[i + 4],  s2 = bucksrc[i + 8],  s3 = bucksrc[i + 12];
        int s4 = bucksrc[i + 16], s5 = bucksrc[i + 20], s6 = bucksrc[i + 24], s7 = bucksrc[i + 28];
        uint4 q0 = T[(size_t)s0 * 16 + ch];
        uint4 q1 = T[(size_t)s1 * 16 + ch];
        uint4 q2 = T[(size_t)s2 * 16 + ch];
        uint4 q3 = T[(size_t)s3 * 16 + ch];
        uint4 q4 = T[(size_t)s4 * 16 + ch];
        uint4 q5 = T[(size_t)s5 * 16 + ch];
        uint4 q6 = T[(size_t)s6 * 16 + ch];
        uint4 q7 = T[(size_t)s7 * 16 + ch];
        float v[8];
        unpack8(q0, v);
#pragma unroll
        for (int j = 0; j < 8; ++j) acc[j] += v[j];
        unpack8(q1, v);
#pragma unroll
        for (int j = 0; j < 8; ++j) acc[j] += v[j];
        unpack8(q2, v);
#pragma unroll
        for (int j = 0; j < 8; ++j) acc[j] += v[j];
        unpack8(q3, v);
#pragma unroll
        for (int j = 0; j < 8; ++j) acc[j] += v[j];
        unpack8(q4, v);
#pragma unroll
        for (int j = 0; j < 8; ++j) acc[j] += v[j];
        unpack8(q5, v);
#pragma unroll
        for (int j = 0; j < 8; ++j) acc[j] += v[j];
        unpack8(q6, v);
#pragma unroll
        for (int j = 0; j < 8; ++j) acc[j] += v[j];
        unpack8(q7, v);
#pragma unroll
        for (int j = 0; j < 8; ++j) acc[j] += v[j];
    }
    for (; i < bnd; i += 4) {
        uint4 q = T[(size_t)bucksrc[i] * 16 + ch];
        float v[8];
        unpack8(q, v);
#pragma unroll
        for (int j = 0; j < 8; ++j) acc[j] += v[j];
    }

#pragma unroll
    for (int j = 0; j < 8; ++j) {
        acc[j] += __shfl_xor(acc[j], 16, 64);
        acc[j] += __shfl_xor(acc[j], 32, 64);
    }
    if (es == 0) {
#pragma unroll
        for (int j = 0; j < 8; ++j) xs[nd][ch * 8 + j] = acc[j];
    }
    __syncthreads();

    // matvec: threads 0..OUT-1, FOUR nodes per thread (W row loaded once)
    if (t < OUT) {
        const float4* wrow = reinterpret_cast<const float4*>(&Wm[(size_t)t * 128]);
        float a0 = 0.f, a1 = 0.f, a2 = 0.f, a3 = 0.f;
#pragma unroll 8
        for (int k4 = 0; k4 < 32; ++k4) {
            float4 w  = wrow[k4];
            float4 x0 = *reinterpret_cast<const float4*>(&xs[0][k4 * 4]);
            float4 x1 = *reinterpret_cast<const float4*>(&xs[1][k4 * 4]);
            float4 x2 = *reinterpret_cast<const float4*>(&xs[2][k4 * 4]);
            float4 x3 = *reinterpret_cast<const float4*>(&xs[3][k4 * 4]);
            a0 += w.x * x0.x + w.y * x0.y + w.z * x0.z + w.w * x0.w;
            a1 += w.x * x1.x + w.y * x1.y + w.z * x1.z + w.w * x1.w;
            a2 += w.x * x2.x + w.y * x2.y + w.z * x2.z + w.w * x2.w;
            a3 += w.x * x3.x + w.y * x3.y + w.z * x3.z + w.w * x3.w;
        }
        int nb = blockIdx.x * 4;
        Z[(size_t)(nb + 0) * OUT + t] = (unsigned short)f2bf(a0);
        Z[(size_t)(nb + 1) * OUT + t] = (unsigned short)f2bf(a1);
        Z[(size_t)(nb + 2) * OUT + t] = (unsigned short)f2bf(a2);
        Z[(size_t)(nb + 3) * OUT + t] = (unsigned short)f2bf(a3);
    }
}

// ---------- final edge output (proven) ----------
__global__ __launch_bounds__(256) void edge_out(const uint4* __restrict__ z5,
                                                const float* __restrict__ b5,
                                                const int* __restrict__ src,
                                                const int* __restrict__ dst,
                                                float4* __restrict__ outp) {
    int t = blockIdx.x * 256 + threadIdx.x;
    int e = t >> 3, ch = t & 7;
    if (e < NE) {
        float va[8], vb[8];
        unpack8(z5[(size_t)src[e] * 8 + ch], va);
        unpack8(z5[(size_t)dst[e] * 8 + ch], vb);
        float4 r0, r1;
        r0.x = 0.5f * (va[0] + vb[0]) + b5[ch * 8 + 0];
        r0.y = 0.5f * (va[1] + vb[1]) + b5[ch * 8 + 1];
        r0.z = 0.5f * (va[2] + vb[2]) + b5[ch * 8 + 2];
        r0.w = 0.5f * (va[3] + vb[3]) + b5[ch * 8 + 3];
        r1.x = 0.5f * (va[4] + vb[4]) + b5[ch * 8 + 4];
        r1.y = 0.5f * (va[5] + vb[5]) + b5[ch * 8 + 5];
        r1.z = 0.5f * (va[6] + vb[6]) + b5[ch * 8 + 6];
        r1.w = 0.5f * (va[7] + vb[7]) + b5[ch * 8 + 7];
        outp[(size_t)e * 16 + ch * 2 + 0] = r0;
        outp[(size_t)e * 16 + ch * 2 + 1] = r1;
    }
}

extern "C" void kernel_launch(void* const* d_in, const int* in_sizes, int n_in,
                              void* d_out, int out_size, void* d_ws, size_t ws_size,
                              hipStream_t stream) {
    const float* ef  = (const float*)d_in[0];
    const int*   src = (const int*)d_in[1];
    const int*   dst = (const int*)d_in[2];
    const float* W1 = (const float*)d_in[3];  const float* b1 = (const float*)d_in[4];
    const float* W2 = (const float*)d_in[5];  const float* b2 = (const float*)d_in[6];
    const float* W3 = (const float*)d_in[7];  const float* b3 = (const float*)d_in[8];
    const float* W4 = (const float*)d_in[9];  const float* b4 = (const float*)d_in[10];
    const float* W5 = (const float*)d_in[11]; const float* b5 = (const float*)d_in[12];
    float* out = (float*)d_out;

    char* p = (char*)d_ws;
    auto alloc = [&](size_t bytes) {
        char* r = p;
        p += (bytes + 255) & ~(size_t)255;
        return r;
    };
    int* cnt     = (int*)alloc(NN * 4);
    int* buck    = (int*)alloc((size_t)NN * CAP * 4);
    int* bucksrc = (int*)alloc((size_t)NN * CAP * 4);
    unsigned short* m = (unsigned short*)alloc((size_t)NN * F * 2);  // bf16
    unsigned short* z = (unsigned short*)alloc((size_t)NN * F * 2);  // bf16

    // ---- bucket-CSR build ----
    hipMemsetAsync(cnt, 0, NN * 4, stream);
    bucket_fill<<<(NE + 255) / 256, 256, 0, stream>>>(dst, src, cnt, buck, bucksrc);

    const int G2 = NN / 2;                 // seg_mean: 2 nodes/block
    const int G4 = NN / 4;                 // gathers:  4 nodes/block (wave-per-node)
    const uint4* m4 = (const uint4*)m;
    const uint4* z4 = (const uint4*)z;

    // ---- layer 1 ----
    seg_mean_k<<<G2, BLK, 0, stream>>>((const float4*)ef, buck, cnt, (ushort4*)m);
    sum_gemm_k<128><<<G4, BLK, 0, stream>>>(m4, bucksrc, cnt, W1, z);

    // ---- layers 2..4 (prev layer's edge compute fused into the relu gather) ----
    const float* Wl[3] = {W2, W3, W4};
    const float* bl[3] = {b1, b2, b3};
    for (int L = 0; L < 3; ++L) {
        relu_gather_k<<<G4, BLK, 0, stream>>>(z4, bucksrc, cnt, bl[L], (uint4*)m);
        sum_gemm_k<128><<<G4, BLK, 0, stream>>>(m4, bucksrc, cnt, Wl[L], z);
    }

    // ---- layer 5 ----
    relu_gather_k<<<G4, BLK, 0, stream>>>(z4, bucksrc, cnt, b4, (uint4*)m);
    sum_gemm_k<64><<<G4, BLK, 0, stream>>>(m4, bucksrc, cnt, W5, z);

    // ---- final per-edge output (82 MB write) ----
    edge_out<<<(NE * 8 + 255) / 256, BLK, 0, stream>>>(z4, b5, src, dst, (float4*)out);
}